// Round 3
// baseline (1043.734 us; speedup 1.0000x reference)
//
#include <hip/hip_runtime.h>

#define N_NODES 100000
#define N_EDGES 1600000
#define NTILES (N_NODES / 16)            // 6250 (exact: 100000 = 16*6250)
#define NB_SCAN ((N_NODES + 511) / 512)  // 196

typedef _Float16 half8 __attribute__((ext_vector_type(8)));
typedef _Float16 half4 __attribute__((ext_vector_type(4)));
typedef float floatx4 __attribute__((ext_vector_type(4)));

// ---------------- per-node degree count (global atomics) ----------------
__global__ __launch_bounds__(256) void count_kernel(const int* __restrict__ dst,
                                                    int* __restrict__ cnt) {
    int stride = gridDim.x * 256;
    const int4* d4 = (const int4*)dst;
    for (int e = blockIdx.x * 256 + threadIdx.x; e < N_EDGES / 4; e += stride) {
        int4 d = d4[e];
        atomicAdd(&cnt[d.x], 1);
        atomicAdd(&cnt[d.y], 1);
        atomicAdd(&cnt[d.z], 1);
        atomicAdd(&cnt[d.w], 1);
    }
}

// ---------------- scan phase 1: per-block exclusive scan of counts ----------------
__global__ __launch_bounds__(512) void scan1_kernel(const int* __restrict__ cnt,
                                                    int* __restrict__ excl,   // = cursor buf
                                                    int* __restrict__ bsum) {
    __shared__ int s[512];
    int t = threadIdx.x;
    int i = blockIdx.x * 512 + t;
    int v = (i < N_NODES) ? cnt[i] : 0;
    s[t] = v;
    __syncthreads();
    for (int off = 1; off < 512; off <<= 1) {
        int u = (t >= off) ? s[t - off] : 0;
        __syncthreads();
        s[t] += u;
        __syncthreads();
    }
    if (i < N_NODES) excl[i] = s[t] - v;
    if (t == 511) bsum[blockIdx.x] = s[511];
}

// ---------------- scan phase 2: add block bases, emit offs/cursor/dinv ----------------
__global__ __launch_bounds__(512) void scan2_kernel(const int* __restrict__ cnt,
                                                    const int* __restrict__ bsum,
                                                    int* __restrict__ offs,
                                                    int* __restrict__ cursor,
                                                    float* __restrict__ dinv) {
    __shared__ int bs[256];
    int t = threadIdx.x;
    if (t < NB_SCAN) bs[t] = bsum[t];
    __syncthreads();
    int bid = blockIdx.x;
    int base = 0;
    for (int k = 0; k < bid; k++) base += bs[k];
    int i = bid * 512 + t;
    if (i < N_NODES) {
        int val = base + cursor[i];     // cursor currently holds in-block exclusive
        offs[i] = val;
        cursor[i] = val;
        dinv[i] = rsqrtf((float)cnt[i] + 1.0f);
    }
    if (bid == NB_SCAN - 1 && t == 0) offs[N_NODES] = N_EDGES;
}

// ---------------- scatter: csr[atomic cursor] = src (order within node arbitrary) ----------------
__global__ __launch_bounds__(256) void scatter_kernel(const int* __restrict__ src,
                                                      const int* __restrict__ dst,
                                                      int* __restrict__ cursor,
                                                      int* __restrict__ csr) {
    int stride = gridDim.x * 256;
    const int4* s4 = (const int4*)src;
    const int4* d4 = (const int4*)dst;
    for (int e = blockIdx.x * 256 + threadIdx.x; e < N_EDGES / 4; e += stride) {
        int4 s = s4[e];
        int4 d = d4[e];
        int p0 = atomicAdd(&cursor[d.x], 1); csr[p0] = s.x;
        int p1 = atomicAdd(&cursor[d.y], 1); csr[p1] = s.y;
        int p2 = atomicAdd(&cursor[d.z], 1); csr[p2] = s.z;
        int p3 = atomicAdd(&cursor[d.w], 1); csr[p3] = s.w;
    }
}

// ---------------- prescale: Xs = X * dinv (row-wise) ----------------
__global__ __launch_bounds__(256) void prescale_kernel(const float* __restrict__ X,
                                                       const float* __restrict__ dinv,
                                                       float* __restrict__ Xs) {
    int i = blockIdx.x * 256 + threadIdx.x;  // float4 index
    if (i < N_NODES * 16) {
        float4 v = ((const float4*)X)[i];
        float d = dinv[i >> 4];
        float4 o = make_float4(v.x * d, v.y * d, v.z * d, v.w * d);
        ((float4*)Xs)[i] = o;
    }
}

// ---------------- fused layer: gather 16-node tile -> LDS (f16 hi/lo) -> MFMA -> store ----------------
// A_n = dinv[n] * (Xs[n] + sum_{s in in(n)} Xs[s]);  out = A @ W + b  [* dinv if prescale_out]
// Per wave: group g (lanes 16g..16g+15) gathers nodes t0+4g+q (q=0..3) = tile rows 4g+q.
// MFMA (proven round-2 maps): A row = lane&15; B col = lane&15; k = 32c+8g+j;
// D: col = lane&15 (channel 16t+m), row = 4g+r (node t0+4g+r).
// f16x2 split: A=Ah+Al, W=Wh+Wl; products hh+hl+lh (ll ~2^-22, dropped).
__global__ __launch_bounds__(256, 4) void fused_layer_kernel(
    const float* __restrict__ Xs, const float* __restrict__ dinv,
    const int* __restrict__ offs, const int* __restrict__ csr,
    const float* __restrict__ W, const float* __restrict__ bias,
    float* __restrict__ out, int* __restrict__ tilectr, int prescale_out) {
    // W fragments, shared per block: [t][c][g][m][j]  (quarter-wave-contiguous => conflict-free)
    __shared__ __attribute__((aligned(16))) _Float16 WhL[4096];
    __shared__ __attribute__((aligned(16))) _Float16 WlL[4096];
    // per-wave A tile, stride 72 halfs (144 B) to break bank alignment
    __shared__ __attribute__((aligned(16))) _Float16 AhL[4][1152];
    __shared__ __attribute__((aligned(16))) _Float16 AlL[4][1152];
    __shared__ int sk;

    int tid = threadIdx.x;
    if (tid == 0) sk = *(volatile int*)tilectr;   // advisory (monotonic; stale => only lower)
    __syncthreads();
    if (sk < NTILES) {
        for (int u = tid; u < 4096; u += 256) {
            int kk = u >> 6, col = u & 63;
            int tt = col >> 4, mm = col & 15, cc = kk >> 5, gg = (kk >> 3) & 3, jj = kk & 7;
            float w = W[u];
            _Float16 h = (_Float16)w;
            int di = (tt * 2 + cc) * 512 + gg * 128 + mm * 8 + jj;
            WhL[di] = h;
            WlL[di] = (_Float16)(w - (float)h);
        }
    }
    __syncthreads();

    int lane = tid & 63;
    int wv = tid >> 6;
    int g = lane >> 4;
    int m = lane & 15;
    const float4* Xv = (const float4*)Xs;
    _Float16* Ah = AhL[wv];
    _Float16* Al = AlL[wv];

    for (;;) {
        int tile = 0;
        if (lane == 0) tile = atomicAdd(tilectr, 1);
        tile = __shfl(tile, 0, 64);
        if (tile >= NTILES) break;
        int t0 = tile * 16;

        // ---- gather: 4 independent chains per wave (one per 16-lane group) ----
        for (int q = 0; q < 4; q++) {
            int nd = t0 + 4 * g + q;
            int beg = offs[nd], end = offs[nd + 1];
            float dn = dinv[nd];
            float4 acc = Xv[(size_t)nd * 16 + m];    // own (pre-scaled) row
            int i = beg;
            int sA0 = (i < end) ? csr[i] : 0;
            int sA1 = (i + 1 < end) ? csr[i + 1] : 0;
            int sB0 = (i + 2 < end) ? csr[i + 2] : 0;
            int sB1 = (i + 3 < end) ? csr[i + 3] : 0;
            float4 rA0 = Xv[(size_t)sA0 * 16 + m];
            float4 rA1 = Xv[(size_t)sA1 * 16 + m];
            while (i < end) {
                float4 rB0 = Xv[(size_t)sB0 * 16 + m];
                float4 rB1 = Xv[(size_t)sB1 * 16 + m];
                int sC0 = (i + 4 < end) ? csr[i + 4] : 0;
                int sC1 = (i + 5 < end) ? csr[i + 5] : 0;
                float m1 = (i + 1 < end) ? 1.0f : 0.0f;
                acc.x += rA0.x; acc.y += rA0.y; acc.z += rA0.z; acc.w += rA0.w;
                acc.x = fmaf(rA1.x, m1, acc.x);
                acc.y = fmaf(rA1.y, m1, acc.y);
                acc.z = fmaf(rA1.z, m1, acc.z);
                acc.w = fmaf(rA1.w, m1, acc.w);
                rA0 = rB0; rA1 = rB1; sB0 = sC0; sB1 = sC1;
                i += 2;
            }
            acc.x *= dn; acc.y *= dn; acc.z *= dn; acc.w *= dn;
            int r = 4 * g + q;
            half4 h4, l4;
            h4[0] = (_Float16)acc.x; l4[0] = (_Float16)(acc.x - (float)h4[0]);
            h4[1] = (_Float16)acc.y; l4[1] = (_Float16)(acc.y - (float)h4[1]);
            h4[2] = (_Float16)acc.z; l4[2] = (_Float16)(acc.z - (float)h4[2]);
            h4[3] = (_Float16)acc.w; l4[3] = (_Float16)(acc.w - (float)h4[3]);
            *(half4*)&Ah[r * 72 + 4 * m] = h4;
            *(half4*)&Al[r * 72 + 4 * m] = l4;
        }
        // same-wave LDS write->read: in-order LDS pipe + compiler lgkmcnt; fence reordering.
        __builtin_amdgcn_wave_barrier();

        // ---- A fragments: row m, k = 32c+8g+j ----
        half8 fah0 = *(const half8*)&Ah[m * 72 + 8 * g];
        half8 fah1 = *(const half8*)&Ah[m * 72 + 32 + 8 * g];
        half8 fal0 = *(const half8*)&Al[m * 72 + 8 * g];
        half8 fal1 = *(const half8*)&Al[m * 72 + 32 + 8 * g];

        float dvq[4];
#pragma unroll
        for (int r = 0; r < 4; r++) dvq[r] = dinv[t0 + 4 * g + r];

#pragma unroll
        for (int t = 0; t < 4; t++) {
            floatx4 d4 = {0.f, 0.f, 0.f, 0.f};
            {
                half8 bwh = *(const half8*)&WhL[(t * 2 + 0) * 512 + g * 128 + m * 8];
                half8 bwl = *(const half8*)&WlL[(t * 2 + 0) * 512 + g * 128 + m * 8];
                d4 = __builtin_amdgcn_mfma_f32_16x16x32_f16(fah0, bwh, d4, 0, 0, 0);
                d4 = __builtin_amdgcn_mfma_f32_16x16x32_f16(fah0, bwl, d4, 0, 0, 0);
                d4 = __builtin_amdgcn_mfma_f32_16x16x32_f16(fal0, bwh, d4, 0, 0, 0);
            }
            {
                half8 bwh = *(const half8*)&WhL[(t * 2 + 1) * 512 + g * 128 + m * 8];
                half8 bwl = *(const half8*)&WlL[(t * 2 + 1) * 512 + g * 128 + m * 8];
                d4 = __builtin_amdgcn_mfma_f32_16x16x32_f16(fah1, bwh, d4, 0, 0, 0);
                d4 = __builtin_amdgcn_mfma_f32_16x16x32_f16(fah1, bwl, d4, 0, 0, 0);
                d4 = __builtin_amdgcn_mfma_f32_16x16x32_f16(fal1, bwh, d4, 0, 0, 0);
            }
            float bv = bias[16 * t + m];
#pragma unroll
            for (int r = 0; r < 4; r++) {
                float v = d4[r] + bv;
                if (prescale_out) v *= dvq[r];
                out[(size_t)(t0 + 4 * g + r) * 64 + 16 * t + m] = v;
            }
        }
        // don't let next tile's LDS writes pass this tile's fragment reads
        __builtin_amdgcn_wave_barrier();
    }
}

extern "C" void kernel_launch(void* const* d_in, const int* in_sizes, int n_in,
                              void* d_out, int out_size, void* d_ws, size_t ws_size,
                              hipStream_t stream) {
    const float* emb = (const float*)d_in[0];
    const int* edge  = (const int*)d_in[1];
    const float* W1 = (const float*)d_in[2];
    const float* b1 = (const float*)d_in[3];
    const float* W2 = (const float*)d_in[4];
    const float* b2 = (const float*)d_in[5];
    const float* W3 = (const float*)d_in[6];
    const float* b3 = (const float*)d_in[7];
    float* out = (float*)d_out;

    const int* src = edge;
    const int* dst = edge + N_EDGES;

    char* ws = (char*)d_ws;
    size_t off = 0;
    int* cnt = (int*)(ws + off);        off += 400128;
    int* offs = (int*)(ws + off);       off += 400128;   // N_NODES+1
    int* cursor = (int*)(ws + off);     off += 400128;
    float* dinv = (float*)(ws + off);   off += 400128;
    int* bsum = (int*)(ws + off);       off += 1024;     // NB_SCAN
    int* tilectr = (int*)(ws + off);    off += 1024;     // 3 layer counters
    int* csr = (int*)(ws + off);        off += 6400128;
    float* Xa = (float*)(ws + off);     off += 25600000;
    float* Xb = (float*)(ws + off);     // 25.6 MB

    // ---- CSR build (shared by all 3 layers); order within node is arbitrary ----
    hipMemsetAsync(cnt, 0, N_NODES * sizeof(int), stream);
    hipMemsetAsync(tilectr, 0, 64, stream);
    count_kernel<<<512, 256, 0, stream>>>(dst, cnt);
    scan1_kernel<<<NB_SCAN, 512, 0, stream>>>(cnt, cursor, bsum);
    scan2_kernel<<<NB_SCAN, 512, 0, stream>>>(cnt, bsum, offs, cursor, dinv);
    scatter_kernel<<<512, 256, 0, stream>>>(src, dst, cursor, csr);

    // Xs1 = emb * dinv  -> Xa
    prescale_kernel<<<(N_NODES * 16 + 255) / 256, 256, 0, stream>>>(emb, dinv, Xa);

    // ---- 3 fused layers (gather + MFMA matmul in one kernel) ----
    fused_layer_kernel<<<2048, 256, 0, stream>>>(Xa, dinv, offs, csr, W1, b1, Xb, tilectr + 0, 1);
    fused_layer_kernel<<<2048, 256, 0, stream>>>(Xb, dinv, offs, csr, W2, b2, Xa, tilectr + 1, 1);
    fused_layer_kernel<<<2048, 256, 0, stream>>>(Xa, dinv, offs, csr, W3, b3, out, tilectr + 2, 0);
}

// Round 4
// 417.860 us; speedup vs baseline: 2.4978x; 2.4978x over previous
//
#include <hip/hip_runtime.h>

#define N_NODES 100000
#define N_EDGES 1600000
#define NTILES (N_NODES / 16)            // 6250 exactly (100000 = 16*6250)

#define BKT_SHIFT 8
#define BKT_NODES 256
#define NBK ((N_NODES + BKT_NODES - 1) / BKT_NODES)      // 391 buckets
#define CHUNK 2048
#define NCHUNKS ((N_EDGES + CHUNK - 1) / CHUNK)          // 782 chunks
#define BCAP 6144                                        // LDS cap per bucket (avg 4096, ~32 sigma)

typedef _Float16 half8 __attribute__((ext_vector_type(8)));
typedef float floatx4 __attribute__((ext_vector_type(4)));

// ---------------- bucket-level histogram (391 bins) ----------------
__global__ __launch_bounds__(512) void bhist_kernel(const int* __restrict__ dst,
                                                    int* __restrict__ bhist) {
    __shared__ int h[NBK];
    for (int i = threadIdx.x; i < NBK; i += 512) h[i] = 0;
    __syncthreads();
    int stride = gridDim.x * 512;
    for (int e = blockIdx.x * 512 + threadIdx.x; e < N_EDGES; e += stride)
        atomicAdd(&h[dst[e] >> BKT_SHIFT], 1);
    __syncthreads();
    for (int i = threadIdx.x; i < NBK; i += 512) {
        int v = h[i];
        if (v) atomicAdd(&bhist[i], v);
    }
}

// ---------------- single-block scan of bucket histogram ----------------
__global__ __launch_bounds__(512) void scan_bhist_kernel(const int* __restrict__ bhist,
                                                         int* __restrict__ bbase,
                                                         int* __restrict__ bcursor) {
    __shared__ int s[512];
    int t = threadIdx.x;
    int v = (t < NBK) ? bhist[t] : 0;
    s[t] = v;
    __syncthreads();
    for (int off = 1; off < 512; off <<= 1) {
        int u = (t >= off) ? s[t - off] : 0;
        __syncthreads();
        s[t] += u;
        __syncthreads();
    }
    if (t < NBK) {
        int excl = s[t] - v;
        bbase[t] = excl;
        bcursor[t] = excl;
    }
    if (t == 0) bbase[NBK] = N_EDGES;
}

// ---------------- phase A: bin edges by 256-node bucket, coalesced runs ----------------
__global__ __launch_bounds__(512) void binA_kernel(const int* __restrict__ src,
                                                   const int* __restrict__ dst,
                                                   int* __restrict__ bcursor,
                                                   int2* __restrict__ csr_tmp) {
    __shared__ int2 staged[CHUNK];   // 16 KB
    __shared__ int delta[CHUNK];     // 8 KB
    __shared__ int hist[NBK];
    __shared__ int lcur[NBK];
    __shared__ int gdel[NBK];
    __shared__ int scan_s[512];
    int t = threadIdx.x;
    int e0 = blockIdx.x * CHUNK;
    int n = N_EDGES - e0; if (n > CHUNK) n = CHUNK;

    for (int i = t; i < NBK; i += 512) hist[i] = 0;
    __syncthreads();
    for (int i = t; i < n; i += 512) atomicAdd(&hist[dst[e0 + i] >> BKT_SHIFT], 1);
    __syncthreads();
    int v = (t < NBK) ? hist[t] : 0;
    scan_s[t] = v;
    __syncthreads();
    for (int off = 1; off < 512; off <<= 1) {
        int u = (t >= off) ? scan_s[t - off] : 0;
        __syncthreads();
        scan_s[t] += u;
        __syncthreads();
    }
    if (t < NBK) {
        int excl = scan_s[t] - v;
        lcur[t] = excl;
        int g = atomicAdd(&bcursor[t], v);  // reserve contiguous run in bucket region
        gdel[t] = g - excl;
    }
    __syncthreads();
    for (int i = t; i < n; i += 512) {
        int s = src[e0 + i];
        int d = dst[e0 + i];
        int bkt = d >> BKT_SHIFT;
        int slot = atomicAdd(&lcur[bkt], 1);
        staged[slot] = make_int2(s, d);
        delta[slot] = gdel[bkt];
    }
    __syncthreads();
    for (int p = t; p < n; p += 512) csr_tmp[delta[p] + p] = staged[p];
}

// ---------------- phase B: per-bucket hist/scan/offs/dinv + CSR ordering (512 thr) ----------------
__global__ __launch_bounds__(512) void binB_kernel(const int* __restrict__ bbase,
                                                   const int2* __restrict__ csr_tmp,
                                                   int* __restrict__ offs,
                                                   float* __restrict__ dinv,
                                                   int* __restrict__ csr) {
    __shared__ int src_s[BCAP];            // 24 KB
    __shared__ unsigned char dloc[BCAP];   // 6 KB
    __shared__ int out_s[BCAP];            // 24 KB
    __shared__ int lcnt[BKT_NODES];
    __shared__ int ss[512];
    __shared__ int lcur[BKT_NODES];
    int t = threadIdx.x;
    int node0 = blockIdx.x * BKT_NODES;
    int base = bbase[blockIdx.x];
    int cnt = bbase[blockIdx.x + 1] - base;
    if (t < BKT_NODES) lcnt[t] = 0;
    __syncthreads();
    bool fits = (cnt <= BCAP);
    if (fits) {
        for (int i = t; i < cnt; i += 512) {
            int2 e = csr_tmp[base + i];
            int dl = e.y - node0;
            src_s[i] = e.x;
            dloc[i] = (unsigned char)dl;
            atomicAdd(&lcnt[dl], 1);
        }
    } else {
        for (int i = t; i < cnt; i += 512) atomicAdd(&lcnt[csr_tmp[base + i].y - node0], 1);
    }
    __syncthreads();
    int v = (t < BKT_NODES) ? lcnt[t] : 0;
    ss[t] = v;
    __syncthreads();
    for (int off = 1; off < 512; off <<= 1) {
        int u = (t >= off) ? ss[t - off] : 0;
        __syncthreads();
        ss[t] += u;
        __syncthreads();
    }
    int excl = ss[t] - v;
    int node = node0 + t;
    if (t < BKT_NODES) {
        lcur[t] = excl;
        if (node < N_NODES) {
            offs[node] = base + excl;
            dinv[node] = rsqrtf((float)v + 1.0f);
        }
    }
    if (blockIdx.x == NBK - 1 && t == 0) offs[N_NODES] = N_EDGES;
    __syncthreads();
    if (fits) {
        for (int i = t; i < cnt; i += 512) {
            int slot = atomicAdd(&lcur[dloc[i]], 1);
            out_s[slot] = src_s[i];
        }
        __syncthreads();
        for (int i = t; i < cnt; i += 512) csr[base + i] = out_s[i];
    } else {
        for (int i = t; i < cnt; i += 512) {
            int2 e = csr_tmp[base + i];
            int slot = atomicAdd(&lcur[e.y - node0], 1);
            csr[base + slot] = e.x;
        }
    }
}

// ---------------- prescale: Xs = X * dinv (row-wise) ----------------
__global__ __launch_bounds__(256) void prescale_kernel(const float* __restrict__ X,
                                                       const float* __restrict__ dinv,
                                                       float* __restrict__ Xs) {
    int i = blockIdx.x * 256 + threadIdx.x;  // float4 index
    if (i < N_NODES * 16) {
        float4 v = ((const float4*)X)[i];
        float d = dinv[i >> 4];
        float4 o = make_float4(v.x * d, v.y * d, v.z * d, v.w * d);
        ((float4*)Xs)[i] = o;
    }
}

// ---------------- pure gather: Agg[n] = dinv[n] * (Xs[n] + sum_{s in in(n)} Xs[s]) ----------------
// quad-stream edge loop: 16 edges/iteration/wave, 16 row loads + 4 csr prefetches in flight
__global__ __launch_bounds__(256) void gather_kernel(
    const float* __restrict__ Xs, const float* __restrict__ dinv,
    const int* __restrict__ offs, const int* __restrict__ csr,
    float* __restrict__ Agg, int n_waves) {
    int lane = threadIdx.x & 63;
    int wid = (blockIdx.x * blockDim.x + threadIdx.x) >> 6;
    int sub = lane >> 4;       // 0..3: edge slot within 4-group
    int l16 = lane & 15;       // 4-channel group
    const float4* Xv = (const float4*)Xs;
    float4* Av = (float4*)Agg;

    for (int node = wid; node < N_NODES; node += n_waves) {
        float di = dinv[node];
        int beg = offs[node], end = offs[node + 1];
        float4 acc;
        if (sub == 0) {
            acc = Xv[node * 16 + l16];          // own (pre-scaled) row
        } else {
            acc = make_float4(0.f, 0.f, 0.f, 0.f);
        }
        // stream k handles edges i+4k, step 16; depth-2 row prefetch per stream
        int i = beg + sub;
        int sA0 = (i      < end) ? csr[i]      : 0;
        int sA1 = (i + 4  < end) ? csr[i + 4]  : 0;
        int sA2 = (i + 8  < end) ? csr[i + 8]  : 0;
        int sA3 = (i + 12 < end) ? csr[i + 12] : 0;
        int sB0 = (i + 16 < end) ? csr[i + 16] : 0;
        int sB1 = (i + 20 < end) ? csr[i + 20] : 0;
        int sB2 = (i + 24 < end) ? csr[i + 24] : 0;
        int sB3 = (i + 28 < end) ? csr[i + 28] : 0;
        float4 rA0 = Xv[(size_t)sA0 * 16 + l16];
        float4 rA1 = Xv[(size_t)sA1 * 16 + l16];
        float4 rA2 = Xv[(size_t)sA2 * 16 + l16];
        float4 rA3 = Xv[(size_t)sA3 * 16 + l16];
        while (i < end) {
            float4 rB0 = Xv[(size_t)sB0 * 16 + l16];
            float4 rB1 = Xv[(size_t)sB1 * 16 + l16];
            float4 rB2 = Xv[(size_t)sB2 * 16 + l16];
            float4 rB3 = Xv[(size_t)sB3 * 16 + l16];
            int sC0 = (i + 32 < end) ? csr[i + 32] : 0;
            int sC1 = (i + 36 < end) ? csr[i + 36] : 0;
            int sC2 = (i + 40 < end) ? csr[i + 40] : 0;
            int sC3 = (i + 44 < end) ? csr[i + 44] : 0;
            float m1 = (i + 4  < end) ? 1.0f : 0.0f;   // stream0 covered by loop cond
            float m2 = (i + 8  < end) ? 1.0f : 0.0f;
            float m3 = (i + 12 < end) ? 1.0f : 0.0f;
            acc.x += rA0.x; acc.y += rA0.y; acc.z += rA0.z; acc.w += rA0.w;
            acc.x = fmaf(rA1.x, m1, acc.x); acc.y = fmaf(rA1.y, m1, acc.y);
            acc.z = fmaf(rA1.z, m1, acc.z); acc.w = fmaf(rA1.w, m1, acc.w);
            acc.x = fmaf(rA2.x, m2, acc.x); acc.y = fmaf(rA2.y, m2, acc.y);
            acc.z = fmaf(rA2.z, m2, acc.z); acc.w = fmaf(rA2.w, m2, acc.w);
            acc.x = fmaf(rA3.x, m3, acc.x); acc.y = fmaf(rA3.y, m3, acc.y);
            acc.z = fmaf(rA3.z, m3, acc.z); acc.w = fmaf(rA3.w, m3, acc.w);
            rA0 = rB0; rA1 = rB1; rA2 = rB2; rA3 = rB3;
            sB0 = sC0; sB1 = sC1; sB2 = sC2; sB3 = sC3;
            i += 16;
        }
        // reduce across the 4 subs
        acc.x += __shfl_xor(acc.x, 16, 64); acc.y += __shfl_xor(acc.y, 16, 64);
        acc.z += __shfl_xor(acc.z, 16, 64); acc.w += __shfl_xor(acc.w, 16, 64);
        acc.x += __shfl_xor(acc.x, 32, 64); acc.y += __shfl_xor(acc.y, 32, 64);
        acc.z += __shfl_xor(acc.z, 32, 64); acc.w += __shfl_xor(acc.w, 32, 64);
        if (sub == 0) {
            acc.x *= di; acc.y *= di; acc.z *= di; acc.w *= di;
            Av[node * 16 + l16] = acc;
        }
    }
}

// ---------------- MFMA dense epilogue: out = (A @ W + b) [* dinv] ----------------
// f16x2 split precision: A = Ah + Al, W = Wh + Wl (each f16); fp32-accumulated
// mfma products hh + hl + lh + ll reconstruct fp32-quality A@W.
// mfma_f32_16x16x32_f16 layouts: A row = lane&15; B col = lane&15;
// D: col = lane&15, row = (lane>>4)*4 + reg. k-position map is a free bijection
// as long as A and B fragments use the same one (k = 32c + 8*(lane>>4) + j).
// Grid-stride over 16-node tiles: W fragments loaded once per wave, ~3 tiles/wave.
__global__ __launch_bounds__(256) void mlp_mfma_kernel(
    const float* __restrict__ A, const float* __restrict__ W,
    const float* __restrict__ b, const float* __restrict__ dinv,
    float* __restrict__ out, int n_waves, int prescale_out) {
    int l = threadIdx.x & 63;
    int wv = threadIdx.x >> 6;
    int m = l & 15;            // A row / B col / D col
    int g = l >> 4;            // k-group
    int wid = blockIdx.x * 4 + wv;

    // ---- W fragments (hoisted once per wave; ~64 VGPRs) ----
    half8 wh[4][2], wl[4][2];
#pragma unroll
    for (int t = 0; t < 4; t++) {
#pragma unroll
        for (int c = 0; c < 2; c++) {
#pragma unroll
            for (int j = 0; j < 8; j++) {
                float w = W[(32 * c + 8 * g + j) * 64 + 16 * t + m];
                _Float16 h = (_Float16)w;
                wh[t][c][j] = h;
                wl[t][c][j] = (_Float16)(w - (float)h);
            }
        }
    }
    float bfrag[4];
#pragma unroll
    for (int t = 0; t < 4; t++) bfrag[t] = b[16 * t + m];

    const float4* Avv = (const float4*)A;

    for (int tile = wid; tile < NTILES; tile += n_waves) {
        int node0 = tile * 16;
        int row = node0 + m;                 // exact: no tail (100000 = 16*6250)
        half8 ah[2], al[2];
#pragma unroll
        for (int c = 0; c < 2; c++) {
            float4 a0 = Avv[(size_t)row * 16 + 8 * c + 2 * g];
            float4 a1 = Avv[(size_t)row * 16 + 8 * c + 2 * g + 1];
            float av[8] = {a0.x, a0.y, a0.z, a0.w, a1.x, a1.y, a1.z, a1.w};
#pragma unroll
            for (int j = 0; j < 8; j++) {
                _Float16 h = (_Float16)av[j];
                ah[c][j] = h;
                al[c][j] = (_Float16)(av[j] - (float)h);
            }
        }

        floatx4 acc[4];
#pragma unroll
        for (int t = 0; t < 4; t++) { acc[t][0] = 0.f; acc[t][1] = 0.f; acc[t][2] = 0.f; acc[t][3] = 0.f; }

#pragma unroll
        for (int c = 0; c < 2; c++) {
#pragma unroll
            for (int t = 0; t < 4; t++) {
                acc[t] = __builtin_amdgcn_mfma_f32_16x16x32_f16(ah[c], wh[t][c], acc[t], 0, 0, 0);
                acc[t] = __builtin_amdgcn_mfma_f32_16x16x32_f16(ah[c], wl[t][c], acc[t], 0, 0, 0);
                acc[t] = __builtin_amdgcn_mfma_f32_16x16x32_f16(al[c], wh[t][c], acc[t], 0, 0, 0);
                acc[t] = __builtin_amdgcn_mfma_f32_16x16x32_f16(al[c], wl[t][c], acc[t], 0, 0, 0);
            }
        }

        float dv[4];
#pragma unroll
        for (int r = 0; r < 4; r++) dv[r] = dinv[node0 + 4 * g + r];
#pragma unroll
        for (int t = 0; t < 4; t++) {
#pragma unroll
            for (int r = 0; r < 4; r++) {
                float v = acc[t][r] + bfrag[t];
                if (prescale_out) v *= dv[r];
                out[(size_t)(node0 + 4 * g + r) * 64 + 16 * t + m] = v;
            }
        }
    }
}

extern "C" void kernel_launch(void* const* d_in, const int* in_sizes, int n_in,
                              void* d_out, int out_size, void* d_ws, size_t ws_size,
                              hipStream_t stream) {
    const float* emb = (const float*)d_in[0];
    const int* edge  = (const int*)d_in[1];
    const float* W1 = (const float*)d_in[2];
    const float* b1 = (const float*)d_in[3];
    const float* W2 = (const float*)d_in[4];
    const float* b2 = (const float*)d_in[5];
    const float* W3 = (const float*)d_in[6];
    const float* b3 = (const float*)d_in[7];
    float* out = (float*)d_out;

    const int* src = edge;
    const int* dst = edge + N_EDGES;

    char* ws = (char*)d_ws;
    size_t off = 0;
    int* bhist = (int*)(ws + off);      off += 2048;
    int* bbase = (int*)(ws + off);      off += 2048;     // NBK+1
    int* bcursor = (int*)(ws + off);    off += 2048;
    int* offs = (int*)(ws + off);       off += 400128;   // N_NODES+1
    float* dinv = (float*)(ws + off);   off += 400128;
    int2* csr_tmp = (int2*)(ws + off);  off += 12800128;
    int* csr = (int*)(ws + off);        off += 6400128;
    float* Xa = (float*)(ws + off);     off += 25600000;
    float* Xb = (float*)(ws + off);     // 25.6 MB

    // ---- CSR build (shared by all 3 layers) ----
    hipMemsetAsync(bhist, 0, NBK * sizeof(int), stream);
    bhist_kernel<<<64, 512, 0, stream>>>(dst, bhist);
    scan_bhist_kernel<<<1, 512, 0, stream>>>(bhist, bbase, bcursor);
    binA_kernel<<<NCHUNKS, 512, 0, stream>>>(src, dst, bcursor, csr_tmp);
    binB_kernel<<<NBK, 512, 0, stream>>>(bbase, csr_tmp, offs, dinv, csr);

    // Xs1 = emb * dinv  -> Xa
    prescale_kernel<<<(N_NODES * 16 + 255) / 256, 256, 0, stream>>>(emb, dinv, Xa);

    const int GBLOCKS = 2048;                 // 8192 waves
    const int n_waves = GBLOCKS * 256 / 64;
    const int MBLOCKS = 512;                  // 2048 waves, ~3 tiles/wave
    const int m_waves = MBLOCKS * 256 / 64;

    // layer 1
    gather_kernel<<<GBLOCKS, 256, 0, stream>>>(Xa, dinv, offs, csr, Xb, n_waves);
    mlp_mfma_kernel<<<MBLOCKS, 256, 0, stream>>>(Xb, W1, b1, dinv, Xa, m_waves, 1);
    // layer 2
    gather_kernel<<<GBLOCKS, 256, 0, stream>>>(Xa, dinv, offs, csr, Xb, n_waves);
    mlp_mfma_kernel<<<MBLOCKS, 256, 0, stream>>>(Xb, W2, b2, dinv, Xa, m_waves, 1);
    // layer 3 (no prescale on final output)
    gather_kernel<<<GBLOCKS, 256, 0, stream>>>(Xa, dinv, offs, csr, Xb, n_waves);
    mlp_mfma_kernel<<<MBLOCKS, 256, 0, stream>>>(Xb, W3, b3, dinv, out, m_waves, 0);
}

// Round 5
// 359.285 us; speedup vs baseline: 2.9050x; 1.1630x over previous
//
#include <hip/hip_runtime.h>

#define N_NODES 100000
#define N_EDGES 1600000
#define NTILES (N_NODES / 16)            // 6250 exactly (100000 = 16*6250)

#define BKT_SHIFT 8
#define BKT_NODES 256
#define NBK ((N_NODES + BKT_NODES - 1) / BKT_NODES)      // 391 buckets
#define CHUNK 2048
#define NCHUNKS ((N_EDGES + CHUNK - 1) / CHUNK)          // 782 chunks
#define BCAP 6144                                        // LDS cap per bucket (avg 4096, ~32 sigma)

typedef _Float16 half8 __attribute__((ext_vector_type(8)));
typedef float floatx4 __attribute__((ext_vector_type(4)));

// ---------------- bucket-level histogram (391 bins) ----------------
__global__ __launch_bounds__(512) void bhist_kernel(const int* __restrict__ dst,
                                                    int* __restrict__ bhist) {
    __shared__ int h[NBK];
    for (int i = threadIdx.x; i < NBK; i += 512) h[i] = 0;
    __syncthreads();
    int stride = gridDim.x * 512;
    for (int e = blockIdx.x * 512 + threadIdx.x; e < N_EDGES; e += stride)
        atomicAdd(&h[dst[e] >> BKT_SHIFT], 1);
    __syncthreads();
    for (int i = threadIdx.x; i < NBK; i += 512) {
        int v = h[i];
        if (v) atomicAdd(&bhist[i], v);
    }
}

// ---------------- single-block scan of bucket histogram ----------------
__global__ __launch_bounds__(512) void scan_bhist_kernel(const int* __restrict__ bhist,
                                                         int* __restrict__ bbase,
                                                         int* __restrict__ bcursor) {
    __shared__ int s[512];
    int t = threadIdx.x;
    int v = (t < NBK) ? bhist[t] : 0;
    s[t] = v;
    __syncthreads();
    for (int off = 1; off < 512; off <<= 1) {
        int u = (t >= off) ? s[t - off] : 0;
        __syncthreads();
        s[t] += u;
        __syncthreads();
    }
    if (t < NBK) {
        int excl = s[t] - v;
        bbase[t] = excl;
        bcursor[t] = excl;
    }
    if (t == 0) bbase[NBK] = N_EDGES;
}

// ---------------- phase A: bin edges by 256-node bucket, coalesced runs ----------------
// csr_tmp entry packed: (dst & 255) << 24 | src   (src < 2^17, dloc < 2^8)
__global__ __launch_bounds__(512) void binA_kernel(const int* __restrict__ src,
                                                   const int* __restrict__ dst,
                                                   int* __restrict__ bcursor,
                                                   int* __restrict__ csr_tmp) {
    __shared__ int staged[CHUNK];    // 8 KB
    __shared__ int delta[CHUNK];     // 8 KB
    __shared__ int hist[NBK];
    __shared__ int lcur[NBK];
    __shared__ int gdel[NBK];
    __shared__ int scan_s[512];
    int t = threadIdx.x;
    int e0 = blockIdx.x * CHUNK;
    int n = N_EDGES - e0; if (n > CHUNK) n = CHUNK;

    for (int i = t; i < NBK; i += 512) hist[i] = 0;
    __syncthreads();
    for (int i = t; i < n; i += 512) atomicAdd(&hist[dst[e0 + i] >> BKT_SHIFT], 1);
    __syncthreads();
    int v = (t < NBK) ? hist[t] : 0;
    scan_s[t] = v;
    __syncthreads();
    for (int off = 1; off < 512; off <<= 1) {
        int u = (t >= off) ? scan_s[t - off] : 0;
        __syncthreads();
        scan_s[t] += u;
        __syncthreads();
    }
    if (t < NBK) {
        int excl = scan_s[t] - v;
        lcur[t] = excl;
        int g = atomicAdd(&bcursor[t], v);  // reserve contiguous run in bucket region
        gdel[t] = g - excl;
    }
    __syncthreads();
    for (int i = t; i < n; i += 512) {
        int s = src[e0 + i];
        int d = dst[e0 + i];
        int bkt = d >> BKT_SHIFT;
        int slot = atomicAdd(&lcur[bkt], 1);
        staged[slot] = ((d & 255) << 24) | s;
        delta[slot] = gdel[bkt];
    }
    __syncthreads();
    for (int p = t; p < n; p += 512) csr_tmp[delta[p] + p] = staged[p];
}

// ---------------- phase B: per-bucket hist/scan/offs/dinv + CSR ordering (512 thr) ----------------
__global__ __launch_bounds__(512) void binB_kernel(const int* __restrict__ bbase,
                                                   const int* __restrict__ csr_tmp,
                                                   int* __restrict__ offs,
                                                   float* __restrict__ dinv,
                                                   int* __restrict__ csr) {
    __shared__ int src_s[BCAP];            // 24 KB
    __shared__ unsigned char dloc[BCAP];   // 6 KB
    __shared__ int out_s[BCAP];            // 24 KB
    __shared__ int lcnt[BKT_NODES];
    __shared__ int ss[512];
    __shared__ int lcur[BKT_NODES];
    int t = threadIdx.x;
    int node0 = blockIdx.x * BKT_NODES;
    int base = bbase[blockIdx.x];
    int cnt = bbase[blockIdx.x + 1] - base;
    if (t < BKT_NODES) lcnt[t] = 0;
    __syncthreads();
    bool fits = (cnt <= BCAP);
    if (fits) {
        for (int i = t; i < cnt; i += 512) {
            int e = csr_tmp[base + i];
            int dl = (unsigned int)e >> 24;
            src_s[i] = e & 0x00FFFFFF;
            dloc[i] = (unsigned char)dl;
            atomicAdd(&lcnt[dl], 1);
        }
    } else {
        for (int i = t; i < cnt; i += 512)
            atomicAdd(&lcnt[(unsigned int)csr_tmp[base + i] >> 24], 1);
    }
    __syncthreads();
    int v = (t < BKT_NODES) ? lcnt[t] : 0;
    ss[t] = v;
    __syncthreads();
    for (int off = 1; off < 512; off <<= 1) {
        int u = (t >= off) ? ss[t - off] : 0;
        __syncthreads();
        ss[t] += u;
        __syncthreads();
    }
    int excl = ss[t] - v;
    int node = node0 + t;
    if (t < BKT_NODES) {
        lcur[t] = excl;
        if (node < N_NODES) {
            offs[node] = base + excl;
            dinv[node] = rsqrtf((float)v + 1.0f);
        }
    }
    if (blockIdx.x == NBK - 1 && t == 0) offs[N_NODES] = N_EDGES;
    __syncthreads();
    if (fits) {
        for (int i = t; i < cnt; i += 512) {
            int slot = atomicAdd(&lcur[dloc[i]], 1);
            out_s[slot] = src_s[i];
        }
        __syncthreads();
        for (int i = t; i < cnt; i += 512) csr[base + i] = out_s[i];
    } else {
        for (int i = t; i < cnt; i += 512) {
            int e = csr_tmp[base + i];
            int slot = atomicAdd(&lcur[(unsigned int)e >> 24], 1);
            csr[base + slot] = e & 0x00FFFFFF;
        }
    }
}

// ---------------- prescale: Xs = X * dinv (row-wise) ----------------
__global__ __launch_bounds__(256) void prescale_kernel(const float* __restrict__ X,
                                                       const float* __restrict__ dinv,
                                                       float* __restrict__ Xs) {
    int i = blockIdx.x * 256 + threadIdx.x;  // float4 index
    if (i < N_NODES * 16) {
        float4 v = ((const float4*)X)[i];
        float d = dinv[i >> 4];
        float4 o = make_float4(v.x * d, v.y * d, v.z * d, v.w * d);
        ((float4*)Xs)[i] = o;
    }
}

// ---------------- pure gather: Agg[n] = dinv[n] * (Xs[n] + sum_{s in in(n)} Xs[s]) ----------------
// dual-stream edge loop (proven round-2 config: VGPR 24, occ 77%, 59.7 us)
__global__ __launch_bounds__(256) void gather_kernel(
    const float* __restrict__ Xs, const float* __restrict__ dinv,
    const int* __restrict__ offs, const int* __restrict__ csr,
    float* __restrict__ Agg, int n_waves) {
    int lane = threadIdx.x & 63;
    int wid = (blockIdx.x * blockDim.x + threadIdx.x) >> 6;
    int sub = lane >> 4;       // 0..3: edge slot within 4-group
    int l16 = lane & 15;       // 4-channel group
    const float4* Xv = (const float4*)Xs;
    float4* Av = (float4*)Agg;

    for (int node = wid; node < N_NODES; node += n_waves) {
        float di = dinv[node];
        int beg = offs[node], end = offs[node + 1];
        float4 acc;
        if (sub == 0) {
            acc = Xv[node * 16 + l16];          // own (pre-scaled) row
        } else {
            acc = make_float4(0.f, 0.f, 0.f, 0.f);
        }
        // dual-stream edge loop: 8 edges/iteration, two independent 1KB row
        // loads in flight + 2 csr prefetches (depth-2 per stream)
        int i = beg + sub;                       // stream0: i, i+8, ...  stream1: i+4, i+12, ...
        int sA0 = (i      < end) ? csr[i]      : 0;
        int sA1 = (i + 4  < end) ? csr[i + 4]  : 0;
        int sB0 = (i + 8  < end) ? csr[i + 8]  : 0;
        int sB1 = (i + 12 < end) ? csr[i + 12] : 0;
        float4 rA0 = Xv[(size_t)sA0 * 16 + l16];
        float4 rA1 = Xv[(size_t)sA1 * 16 + l16];
        while (i < end) {
            float4 rB0 = Xv[(size_t)sB0 * 16 + l16];
            float4 rB1 = Xv[(size_t)sB1 * 16 + l16];
            int sC0 = (i + 16 < end) ? csr[i + 16] : 0;
            int sC1 = (i + 20 < end) ? csr[i + 20] : 0;
            float m1 = (i + 4 < end) ? 1.0f : 0.0f;   // stream0 add is covered by loop cond
            acc.x += rA0.x; acc.y += rA0.y; acc.z += rA0.z; acc.w += rA0.w;
            acc.x = fmaf(rA1.x, m1, acc.x);
            acc.y = fmaf(rA1.y, m1, acc.y);
            acc.z = fmaf(rA1.z, m1, acc.z);
            acc.w = fmaf(rA1.w, m1, acc.w);
            rA0 = rB0; rA1 = rB1;
            sB0 = sC0; sB1 = sC1;
            i += 8;
        }
        // reduce across the 4 subs
        acc.x += __shfl_xor(acc.x, 16, 64); acc.y += __shfl_xor(acc.y, 16, 64);
        acc.z += __shfl_xor(acc.z, 16, 64); acc.w += __shfl_xor(acc.w, 16, 64);
        acc.x += __shfl_xor(acc.x, 32, 64); acc.y += __shfl_xor(acc.y, 32, 64);
        acc.z += __shfl_xor(acc.z, 32, 64); acc.w += __shfl_xor(acc.w, 32, 64);
        if (sub == 0) {
            acc.x *= di; acc.y *= di; acc.z *= di; acc.w *= di;
            Av[node * 16 + l16] = acc;
        }
    }
}

// ---------------- MFMA dense epilogue: out = (A @ W + b) [* dinv] ----------------
// f16x2 split precision: A = Ah + Al, W = Wh + Wl (each f16); fp32-accumulated
// mfma products hh + hl + lh + ll reconstruct fp32-quality A@W.
// mfma_f32_16x16x32_f16 layouts: A row = lane&15; B col = lane&15;
// D: col = lane&15, row = (lane>>4)*4 + reg. k-position map is a free bijection
// as long as A and B fragments use the same one (k = 32c + 8*(lane>>4) + j).
// Grid-stride over 16-node tiles: W fragments loaded once per wave, ~3 tiles/wave.
__global__ __launch_bounds__(256) void mlp_mfma_kernel(
    const float* __restrict__ A, const float* __restrict__ W,
    const float* __restrict__ b, const float* __restrict__ dinv,
    float* __restrict__ out, int n_waves, int prescale_out) {
    int l = threadIdx.x & 63;
    int wv = threadIdx.x >> 6;
    int m = l & 15;            // A row / B col / D col
    int g = l >> 4;            // k-group
    int wid = blockIdx.x * 4 + wv;

    // ---- W fragments (hoisted once per wave; ~64 VGPRs) ----
    half8 wh[4][2], wl[4][2];
#pragma unroll
    for (int t = 0; t < 4; t++) {
#pragma unroll
        for (int c = 0; c < 2; c++) {
#pragma unroll
            for (int j = 0; j < 8; j++) {
                float w = W[(32 * c + 8 * g + j) * 64 + 16 * t + m];
                _Float16 h = (_Float16)w;
                wh[t][c][j] = h;
                wl[t][c][j] = (_Float16)(w - (float)h);
            }
        }
    }
    float bfrag[4];
#pragma unroll
    for (int t = 0; t < 4; t++) bfrag[t] = b[16 * t + m];

    const float4* Avv = (const float4*)A;

    for (int tile = wid; tile < NTILES; tile += n_waves) {
        int node0 = tile * 16;
        int row = node0 + m;                 // exact: no tail (100000 = 16*6250)
        half8 ah[2], al[2];
#pragma unroll
        for (int c = 0; c < 2; c++) {
            float4 a0 = Avv[(size_t)row * 16 + 8 * c + 2 * g];
            float4 a1 = Avv[(size_t)row * 16 + 8 * c + 2 * g + 1];
            float av[8] = {a0.x, a0.y, a0.z, a0.w, a1.x, a1.y, a1.z, a1.w};
#pragma unroll
            for (int j = 0; j < 8; j++) {
                _Float16 h = (_Float16)av[j];
                ah[c][j] = h;
                al[c][j] = (_Float16)(av[j] - (float)h);
            }
        }

        floatx4 acc[4];
#pragma unroll
        for (int t = 0; t < 4; t++) { acc[t][0] = 0.f; acc[t][1] = 0.f; acc[t][2] = 0.f; acc[t][3] = 0.f; }

#pragma unroll
        for (int c = 0; c < 2; c++) {
#pragma unroll
            for (int t = 0; t < 4; t++) {
                acc[t] = __builtin_amdgcn_mfma_f32_16x16x32_f16(ah[c], wh[t][c], acc[t], 0, 0, 0);
                acc[t] = __builtin_amdgcn_mfma_f32_16x16x32_f16(ah[c], wl[t][c], acc[t], 0, 0, 0);
                acc[t] = __builtin_amdgcn_mfma_f32_16x16x32_f16(al[c], wh[t][c], acc[t], 0, 0, 0);
                acc[t] = __builtin_amdgcn_mfma_f32_16x16x32_f16(al[c], wl[t][c], acc[t], 0, 0, 0);
            }
        }

        float dv[4];
#pragma unroll
        for (int r = 0; r < 4; r++) dv[r] = dinv[node0 + 4 * g + r];
#pragma unroll
        for (int t = 0; t < 4; t++) {
#pragma unroll
            for (int r = 0; r < 4; r++) {
                float v = acc[t][r] + bfrag[t];
                if (prescale_out) v *= dv[r];
                out[(size_t)(node0 + 4 * g + r) * 64 + 16 * t + m] = v;
            }
        }
    }
}

extern "C" void kernel_launch(void* const* d_in, const int* in_sizes, int n_in,
                              void* d_out, int out_size, void* d_ws, size_t ws_size,
                              hipStream_t stream) {
    const float* emb = (const float*)d_in[0];
    const int* edge  = (const int*)d_in[1];
    const float* W1 = (const float*)d_in[2];
    const float* b1 = (const float*)d_in[3];
    const float* W2 = (const float*)d_in[4];
    const float* b2 = (const float*)d_in[5];
    const float* W3 = (const float*)d_in[6];
    const float* b3 = (const float*)d_in[7];
    float* out = (float*)d_out;

    const int* src = edge;
    const int* dst = edge + N_EDGES;

    char* ws = (char*)d_ws;
    size_t off = 0;
    int* bhist = (int*)(ws + off);      off += 2048;
    int* bbase = (int*)(ws + off);      off += 2048;     // NBK+1
    int* bcursor = (int*)(ws + off);    off += 2048;
    int* offs = (int*)(ws + off);       off += 400128;   // N_NODES+1
    float* dinv = (float*)(ws + off);   off += 400128;
    int* csr_tmp = (int*)(ws + off);    off += 6400128;  // packed (dloc<<24)|src
    int* csr = (int*)(ws + off);        off += 6400128;
    float* Xa = (float*)(ws + off);     off += 25600000;
    float* Xb = (float*)(ws + off);     // 25.6 MB

    // ---- CSR build (shared by all 3 layers) ----
    hipMemsetAsync(bhist, 0, NBK * sizeof(int), stream);
    bhist_kernel<<<64, 512, 0, stream>>>(dst, bhist);
    scan_bhist_kernel<<<1, 512, 0, stream>>>(bhist, bbase, bcursor);
    binA_kernel<<<NCHUNKS, 512, 0, stream>>>(src, dst, bcursor, csr_tmp);
    binB_kernel<<<NBK, 512, 0, stream>>>(bbase, csr_tmp, offs, dinv, csr);

    // Xs1 = emb * dinv  -> Xa
    prescale_kernel<<<(N_NODES * 16 + 255) / 256, 256, 0, stream>>>(emb, dinv, Xa);

    const int GBLOCKS = 2048;                 // 8192 waves (full residency)
    const int n_waves = GBLOCKS * 256 / 64;
    const int MBLOCKS = 512;                  // 2048 waves, ~3 tiles/wave
    const int m_waves = MBLOCKS * 256 / 64;

    // layer 1
    gather_kernel<<<GBLOCKS, 256, 0, stream>>>(Xa, dinv, offs, csr, Xb, n_waves);
    mlp_mfma_kernel<<<MBLOCKS, 256, 0, stream>>>(Xb, W1, b1, dinv, Xa, m_waves, 1);
    // layer 2
    gather_kernel<<<GBLOCKS, 256, 0, stream>>>(Xa, dinv, offs, csr, Xb, n_waves);
    mlp_mfma_kernel<<<MBLOCKS, 256, 0, stream>>>(Xb, W2, b2, dinv, Xa, m_waves, 1);
    // layer 3 (no prescale on final output)
    gather_kernel<<<GBLOCKS, 256, 0, stream>>>(Xa, dinv, offs, csr, Xb, n_waves);
    mlp_mfma_kernel<<<MBLOCKS, 256, 0, stream>>>(Xb, W3, b3, dinv, out, m_waves, 0);
}